// Round 1
// baseline (378.168 us; speedup 1.0000x reference)
//
#include <hip/hip_runtime.h>
#include <cstdint>
#include <cmath>

// Problem constants (fixed by setup_inputs)
#define NROWS 32768
#define HD    1024
#define NMOT  128
#define NCLS  16
#define KSEL  32
#define EPSV  1e-4f

typedef __attribute__((ext_vector_type(4))) float  f32x4;
typedef __attribute__((ext_vector_type(8))) __bf16 bf16x8;
typedef __attribute__((ext_vector_type(4))) __bf16 bf16x4;

// ---- workspace layout (in floats) ----
// wsf[0]        : loss accumulator (atomicAdd target)
// wsf[64..191]  : motif squared norms mn[128]
// wsf[1024 ...] : distT[128][32768]  (motif-major => coalesced row reads)
#define WS_MN 64
#define WS_DT 1024

static __device__ __forceinline__ __bf16 f2bf(float f) {
    unsigned int u = __builtin_bit_cast(unsigned int, f);
    unsigned int r = (u + 0x7fffu + ((u >> 16) & 1u)) >> 16;  // RNE
    unsigned short s = (unsigned short)r;
    return __builtin_bit_cast(__bf16, s);
}

static __device__ __forceinline__ void stv(__bf16* dst, float4 v) {
    bf16x4 t;
    t[0] = f2bf(v.x); t[1] = f2bf(v.y); t[2] = f2bf(v.z); t[3] = f2bf(v.w);
    *(bf16x4*)dst = t;   // ds_write_b64
}

static __device__ __forceinline__ float dot4(float4 v) {
    return v.x * v.x + v.y * v.y + v.z * v.z + v.w * v.w;
}

// ---------------------------------------------------------------------------
// Kernel 1: motif norms + zero the loss accumulator
// ---------------------------------------------------------------------------
__global__ __launch_bounds__(256) void prep_k(const float* __restrict__ mv,
                                              float* __restrict__ wsf) {
    const int j = blockIdx.x;
    float s = 0.f;
    for (int k = threadIdx.x; k < HD; k += 256) {
        float v = mv[(size_t)j * HD + k];
        s += v * v;
    }
#pragma unroll
    for (int o = 1; o < 64; o <<= 1) s += __shfl_xor(s, o, 64);
    __shared__ float red[4];
    if ((threadIdx.x & 63) == 0) red[threadIdx.x >> 6] = s;
    __syncthreads();
    if (threadIdx.x == 0) {
        wsf[WS_MN + j] = red[0] + red[1] + red[2] + red[3];
        if (j == 0) wsf[0] = 0.f;
    }
}

// ---------------------------------------------------------------------------
// Kernel 2: bf16-MFMA GEMM (z @ M^T) fused with ||z||^2 and distance epilogue.
// Tile: 64 rows x 128 cols (all motifs), BK=32. 512 blocks, 256 threads
// (4 waves, each 32x64 = 2x4 grid of 16x16x32 MFMAs).
// ---------------------------------------------------------------------------
#define BM 64
#define BN 128
#define BK 32
#define SA 40   // padded LDS stride in bf16 elems (80B: breaks pow2 bank strides)

__global__ __launch_bounds__(256, 2) void gemm_dist(
    const float* __restrict__ z, const float* __restrict__ mv,
    const float* __restrict__ mn, float* __restrict__ distT) {
    __shared__ __bf16 As[BM * SA];
    __shared__ __bf16 Bs[BN * SA];
    __shared__ float  szn[BM];

    const int tid  = threadIdx.x;
    const int row0 = blockIdx.x * BM;
    const int lane = tid & 63;
    const int wave = tid >> 6;
    const int wr   = wave >> 1;   // 0..1 : 32-row strip
    const int wc   = wave & 1;    // 0..1 : 64-col strip
    const int l15  = lane & 15;
    const int quad = lane >> 4;

    const int sq = tid & 7;       // which float4 within the 32-wide k slab
    const int sr = tid >> 3;      // 0..31 base row for staging

    f32x4 acc[2][4];
#pragma unroll
    for (int i = 0; i < 2; ++i)
#pragma unroll
        for (int j = 0; j < 4; ++j) acc[i][j] = (f32x4){0.f, 0.f, 0.f, 0.f};

    float zsq0 = 0.f, zsq1 = 0.f;

    const float* zb = z + (size_t)(row0 + sr) * HD + sq * 4;
    const float* bb = mv + (size_t)sr * HD + sq * 4;
    float4 a0 = *(const float4*)(zb);
    float4 a1 = *(const float4*)(zb + 32 * HD);
    float4 b0 = *(const float4*)(bb);
    float4 b1 = *(const float4*)(bb + 32 * HD);
    float4 b2 = *(const float4*)(bb + 64 * HD);
    float4 b3 = *(const float4*)(bb + 96 * HD);

    for (int kt = 0; kt < HD / BK; ++kt) {
        __syncthreads();  // previous iteration's frag reads done
        stv(&As[sr * SA + sq * 4], a0);
        stv(&As[(sr + 32) * SA + sq * 4], a1);
        stv(&Bs[sr * SA + sq * 4], b0);
        stv(&Bs[(sr + 32) * SA + sq * 4], b1);
        stv(&Bs[(sr + 64) * SA + sq * 4], b2);
        stv(&Bs[(sr + 96) * SA + sq * 4], b3);
        zsq0 += dot4(a0);
        zsq1 += dot4(a1);
        __syncthreads();
        if (kt + 1 < HD / BK) {   // prefetch next slab; overlaps MFMA below
            const float* zn = zb + (kt + 1) * BK;
            const float* bn = bb + (kt + 1) * BK;
            a0 = *(const float4*)(zn);
            a1 = *(const float4*)(zn + 32 * HD);
            b0 = *(const float4*)(bn);
            b1 = *(const float4*)(bn + 32 * HD);
            b2 = *(const float4*)(bn + 64 * HD);
            b3 = *(const float4*)(bn + 96 * HD);
        }
        const int ko = quad * 8;  // A[m][k=quad*8+j], B[n][k=quad*8+j]
        bf16x8 af[2], bfr[4];
#pragma unroll
        for (int i = 0; i < 2; ++i)
            af[i] = *(const bf16x8*)&As[(wr * 32 + i * 16 + l15) * SA + ko];
#pragma unroll
        for (int j = 0; j < 4; ++j)
            bfr[j] = *(const bf16x8*)&Bs[(wc * 64 + j * 16 + l15) * SA + ko];
#pragma unroll
        for (int i = 0; i < 2; ++i)
#pragma unroll
            for (int j = 0; j < 4; ++j)
                acc[i][j] = __builtin_amdgcn_mfma_f32_16x16x32_bf16(
                    af[i], bfr[j], acc[i][j], 0, 0, 0);
    }

    // reduce ||z||^2 across the 8 staging lanes that share each row
#pragma unroll
    for (int o = 1; o < 8; o <<= 1) {
        zsq0 += __shfl_xor(zsq0, o, 64);
        zsq1 += __shfl_xor(zsq1, o, 64);
    }
    if (sq == 0) { szn[sr] = zsq0; szn[sr + 32] = zsq1; }
    __syncthreads();

    // epilogue: dist = ||z||^2 + ||m||^2 - 2*xp, write motif-major
    // C/D layout: col = lane&15, row = quad*4 + reg  [verified mapping]
    float4 znv[2];
#pragma unroll
    for (int i = 0; i < 2; ++i)
        znv[i] = *(const float4*)&szn[wr * 32 + i * 16 + quad * 4];
#pragma unroll
    for (int j = 0; j < 4; ++j) {
        const int c = wc * 64 + j * 16 + l15;
        const float mc = mn[c];
        float* dcol = distT + (size_t)c * NROWS + row0 + wr * 32;
#pragma unroll
        for (int i = 0; i < 2; ++i) {
            float4 d;
            d.x = znv[i].x + mc - 2.f * acc[i][j][0];
            d.y = znv[i].y + mc - 2.f * acc[i][j][1];
            d.z = znv[i].z + mc - 2.f * acc[i][j][2];
            d.w = znv[i].w + mc - 2.f * acc[i][j][3];
            *(float4*)&dcol[i * 16 + quad * 4] = d;
        }
    }
}

// ---------------------------------------------------------------------------
// Kernel 3: contrastive loss. exp(log(r)/0.2) == r^5 (monotone, exact math).
// ---------------------------------------------------------------------------
__global__ __launch_bounds__(128) void loss_k(const float* __restrict__ distT,
                                              const int* __restrict__ y,
                                              float* __restrict__ lossAcc) {
    const int i = blockIdx.x * 128 + threadIdx.x;
    const int cls = y[i];
    float pmax = -INFINITY, nsum = 0.f;
#pragma unroll 4
    for (int j = 0; j < NMOT; ++j) {
        float d = distT[(size_t)j * NROWS + i];
        float ratio = (d + 1.0f) / (d + EPSV);
        float r2 = ratio * ratio;
        float s = r2 * r2 * ratio;       // ratio^5
        if ((j >> 3) == cls) pmax = fmaxf(pmax, s);
        else nsum += s;
    }
    float li = logf((nsum + pmax) / pmax);  // = -log(pos/(neg+pos))
#pragma unroll
    for (int o = 1; o < 64; o <<= 1) li += __shfl_xor(li, o, 64);
    __shared__ float red[2];
    if ((threadIdx.x & 63) == 0) red[threadIdx.x >> 6] = li;
    __syncthreads();
    if (threadIdx.x == 0) atomicAdd(lossAcc, red[0] + red[1]);
}

// ---------------------------------------------------------------------------
// Kernel 4: per-motif top-32 largest distances among same-class samples,
// gather-mean of the selected z rows, tau-blend, and final loss write.
// ---------------------------------------------------------------------------
#define CAP 4096
__global__ __launch_bounds__(256) void update_k(
    const float* __restrict__ z, const float* __restrict__ mv,
    const int* __restrict__ y, const float* __restrict__ distT,
    const float* __restrict__ lossAcc, float* __restrict__ out) {
    __shared__ float ldv[CAP];
    __shared__ int   lidx[CAP];
    __shared__ int   cnt;
    __shared__ int   sel[KSEL];
    __shared__ float rv[4];
    __shared__ int   ri[4], rp[4];

    const int j = blockIdx.x;
    const int cls = j >> 3;   // motif_class = j // 8
    const int tid = threadIdx.x;
    if (tid == 0) cnt = 0;
    __syncthreads();

    const float* dcol = distT + (size_t)j * NROWS;
    for (int i = tid; i < NROWS; i += 256) {
        if (y[i] == cls) {
            int p = atomicAdd(&cnt, 1);
            if (p < CAP) { ldv[p] = dcol[i]; lidx[p] = i; }
        }
    }
    __syncthreads();
    const int n = cnt < CAP ? cnt : CAP;

    for (int r = 0; r < KSEL; ++r) {
        float bv = -INFINITY;
        int bi = 0x7fffffff, bp = -1;
        for (int p = tid; p < n; p += 256) {
            float v = ldv[p];
            int idx = lidx[p];
            if (v > bv || (v == bv && idx < bi)) { bv = v; bi = idx; bp = p; }
        }
#pragma unroll
        for (int o = 1; o < 64; o <<= 1) {
            float ov = __shfl_xor(bv, o, 64);
            int   oi = __shfl_xor(bi, o, 64);
            int   op = __shfl_xor(bp, o, 64);
            if (ov > bv || (ov == bv && oi < bi)) { bv = ov; bi = oi; bp = op; }
        }
        if ((tid & 63) == 0) { int w = tid >> 6; rv[w] = bv; ri[w] = bi; rp[w] = bp; }
        __syncthreads();
        if (tid == 0) {
            float xv = rv[0]; int xi = ri[0], xp = rp[0];
            for (int w = 1; w < 4; ++w)
                if (rv[w] > xv || (rv[w] == xv && ri[w] < xi)) {
                    xv = rv[w]; xi = ri[w]; xp = rp[w];
                }
            sel[r] = xi;
            ldv[xp] = -INFINITY;   // remove selected entry
        }
        __syncthreads();
    }

    for (int h = tid; h < HD; h += 256) {
        float s = 0.f;
#pragma unroll 8
        for (int k = 0; k < KSEL; ++k) s += z[(size_t)sel[k] * HD + h];
        out[1 + (size_t)j * HD + h] =
            0.99f * mv[(size_t)j * HD + h] + 0.01f * (s * (1.0f / KSEL));
    }
    if (j == 0 && tid == 0) out[0] = *lossAcc * (1.0f / NROWS);
}

// ---------------------------------------------------------------------------
extern "C" void kernel_launch(void* const* d_in, const int* in_sizes, int n_in,
                              void* d_out, int out_size, void* d_ws, size_t ws_size,
                              hipStream_t stream) {
    const float* z  = (const float*)d_in[0];
    const float* mv = (const float*)d_in[1];
    const int*   y  = (const int*)d_in[2];
    float* out = (float*)d_out;
    float* wsf = (float*)d_ws;
    float* mn    = wsf + WS_MN;
    float* distT = wsf + WS_DT;

    hipLaunchKernelGGL(prep_k,    dim3(NMOT),        dim3(256), 0, stream, mv, wsf);
    hipLaunchKernelGGL(gemm_dist, dim3(NROWS / BM),  dim3(256), 0, stream, z, mv, mn, distT);
    hipLaunchKernelGGL(loss_k,    dim3(NROWS / 128), dim3(128), 0, stream, distT, y, wsf);
    hipLaunchKernelGGL(update_k,  dim3(NMOT),        dim3(256), 0, stream, z, mv, y, distT, wsf, out);
}

// Round 2
// 304.521 us; speedup vs baseline: 1.2418x; 1.2418x over previous
//
#include <hip/hip_runtime.h>
#include <cstdint>
#include <cmath>

// Problem constants (fixed by setup_inputs)
#define NROWS 32768
#define HD    1024
#define NMOT  128
#define NCLS  16
#define KSEL  32
#define EPSV  1e-4f

typedef __attribute__((ext_vector_type(4))) float  f32x4;
typedef __attribute__((ext_vector_type(8))) __bf16 bf16x8;
typedef __attribute__((ext_vector_type(4))) __bf16 bf16x4;

// ---- workspace layout (in floats) ----
// wsf[0]              : loss accumulator
// wsf[64..191]        : motif squared norms mn[128]
// wsf[256..65792)     : mvbf — mv converted to bf16 (128x1024)
// wsf[65792..327936)  : cd[32768][8] — per-row distances to its 8 same-class motifs
// wsf[327936..360704) : s1v[1024][32] — stage-1 top-32 values
// wsf[360704..393472) : s1i[1024][32] — stage-1 top-32 indices (as int)
#define WS_MN   64
#define WS_MVBF 256
#define WS_CD   65792
#define WS_S1V  327936
#define WS_S1I  360704

static __device__ __forceinline__ float dot4(float4 v) {
    return v.x * v.x + v.y * v.y + v.z * v.z + v.w * v.w;
}

static __device__ __forceinline__ bf16x4 cvt4(float4 v) {
    bf16x4 t;
    t[0] = (__bf16)v.x; t[1] = (__bf16)v.y; t[2] = (__bf16)v.z; t[3] = (__bf16)v.w;
    return t;
}

// ---------------------------------------------------------------------------
// Kernel 1: motif norms + bf16 copy of mv + zero the loss accumulator
// ---------------------------------------------------------------------------
__global__ __launch_bounds__(256) void prep_k(const float* __restrict__ mv,
                                              float* __restrict__ wsf,
                                              __bf16* __restrict__ mvbf) {
    const int j = blockIdx.x;
    const int k = threadIdx.x * 4;           // 256 threads x 4 = 1024 = HD
    float4 v = *(const float4*)&mv[(size_t)j * HD + k];
    *(bf16x4*)&mvbf[(size_t)j * HD + k] = cvt4(v);
    float s = dot4(v);
#pragma unroll
    for (int o = 1; o < 64; o <<= 1) s += __shfl_xor(s, o, 64);
    __shared__ float red[4];
    if ((threadIdx.x & 63) == 0) red[threadIdx.x >> 6] = s;
    __syncthreads();
    if (threadIdx.x == 0) {
        wsf[WS_MN + j] = red[0] + red[1] + red[2] + red[3];
        if (j == 0) wsf[0] = 0.f;
    }
}

// ---------------------------------------------------------------------------
// Kernel 2: bf16-MFMA GEMM (z @ M^T) fused with ||z||^2, distance epilogue,
// the FULL contrastive loss (per-row reduce + atomicAdd), and a compact
// write of only the 8 same-class distances per row (cd[N][8]).
// Tile: 64 rows x 128 cols (all motifs), BK=32, 512 blocks, 256 threads.
// ---------------------------------------------------------------------------
#define BM 64
#define BN 128
#define BK 32
#define SA 40   // padded LDS stride in bf16 elems (80B)

__global__ __launch_bounds__(256, 3) void gemm_fused(
    const float* __restrict__ z, const __bf16* __restrict__ mvbf,
    const float* __restrict__ mn, float* __restrict__ cd,
    const int* __restrict__ y, float* __restrict__ lossAcc) {
    __shared__ __bf16 As[BM * SA];
    __shared__ __bf16 Bs[BN * SA];
    __shared__ float  szn[BM];
    __shared__ int    ly[BM];
    __shared__ float  spm[2][BM];
    __shared__ float  sns[2][BM];

    const int tid  = threadIdx.x;
    const int row0 = blockIdx.x * BM;
    const int lane = tid & 63;
    const int wave = tid >> 6;
    const int wr   = wave >> 1;   // 0..1 : 32-row strip
    const int wc   = wave & 1;    // 0..1 : 64-col strip
    const int l15  = lane & 15;
    const int quad = lane >> 4;

    const int sq = tid & 7;       // A staging: float4 slot in k-slab
    const int sr = tid >> 3;      // A staging: row 0..31
    const int bq = tid & 3;       // B staging: 16B chunk in k-slab
    const int br = tid >> 2;      // B staging: row 0..63

    if (tid < BM) ly[tid] = y[row0 + tid];

    f32x4 acc[2][4];
#pragma unroll
    for (int i = 0; i < 2; ++i)
#pragma unroll
        for (int j = 0; j < 4; ++j) acc[i][j] = (f32x4){0.f, 0.f, 0.f, 0.f};

    float zsq0 = 0.f, zsq1 = 0.f;

    const float*  zb = z + (size_t)(row0 + sr) * HD + sq * 4;
    const __bf16* bb = mvbf + (size_t)br * HD + bq * 8;
    float4 a0 = *(const float4*)(zb);
    float4 a1 = *(const float4*)(zb + 32 * HD);
    bf16x8 b0 = *(const bf16x8*)(bb);
    bf16x8 b1 = *(const bf16x8*)(bb + 64 * HD);

    for (int kt = 0; kt < HD / BK; ++kt) {
        __syncthreads();  // previous iteration's frag reads done
        *(bf16x4*)&As[sr * SA + sq * 4] = cvt4(a0);
        *(bf16x4*)&As[(sr + 32) * SA + sq * 4] = cvt4(a1);
        *(bf16x8*)&Bs[br * SA + bq * 8] = b0;
        *(bf16x8*)&Bs[(br + 64) * SA + bq * 8] = b1;
        zsq0 += dot4(a0);
        zsq1 += dot4(a1);
        __syncthreads();
        if (kt + 1 < HD / BK) {   // prefetch next slab; overlaps MFMA below
            const float*  zn = zb + (kt + 1) * BK;
            const __bf16* bn = bb + (kt + 1) * BK;
            a0 = *(const float4*)(zn);
            a1 = *(const float4*)(zn + 32 * HD);
            b0 = *(const bf16x8*)(bn);
            b1 = *(const bf16x8*)(bn + 64 * HD);
        }
        const int ko = quad * 8;  // A[m][k=quad*8+j], B[n][k=quad*8+j]
        bf16x8 af[2], bfr[4];
#pragma unroll
        for (int i = 0; i < 2; ++i)
            af[i] = *(const bf16x8*)&As[(wr * 32 + i * 16 + l15) * SA + ko];
#pragma unroll
        for (int j = 0; j < 4; ++j)
            bfr[j] = *(const bf16x8*)&Bs[(wc * 64 + j * 16 + l15) * SA + ko];
#pragma unroll
        for (int i = 0; i < 2; ++i)
#pragma unroll
            for (int j = 0; j < 4; ++j)
                acc[i][j] = __builtin_amdgcn_mfma_f32_16x16x32_bf16(
                    af[i], bfr[j], acc[i][j], 0, 0, 0);
    }

    // reduce ||z||^2 across the 8 staging lanes that share each row
#pragma unroll
    for (int o = 1; o < 8; o <<= 1) {
        zsq0 += __shfl_xor(zsq0, o, 64);
        zsq1 += __shfl_xor(zsq1, o, 64);
    }
    if (sq == 0) { szn[sr] = zsq0; szn[sr + 32] = zsq1; }
    __syncthreads();

    // epilogue: dist = ||z||^2 + ||m||^2 - 2*xp
    // C/D layout: col = lane&15, row = quad*4 + reg  [verified]
    f32x4 znv[2];
    int rcls[2][4];
#pragma unroll
    for (int i = 0; i < 2; ++i) {
        znv[i] = *(const f32x4*)&szn[wr * 32 + i * 16 + quad * 4];
#pragma unroll
        for (int reg = 0; reg < 4; ++reg)
            rcls[i][reg] = ly[wr * 32 + i * 16 + quad * 4 + reg];
    }
    float pm[2][4], ns[2][4];
#pragma unroll
    for (int i = 0; i < 2; ++i)
#pragma unroll
        for (int reg = 0; reg < 4; ++reg) { pm[i][reg] = 0.f; ns[i][reg] = 0.f; }

#pragma unroll
    for (int j = 0; j < 4; ++j) {
        const int c = wc * 64 + j * 16 + l15;
        const float mc = mn[c];
        const int ccls = c >> 3;
#pragma unroll
        for (int i = 0; i < 2; ++i) {
#pragma unroll
            for (int reg = 0; reg < 4; ++reg) {
                const int row = wr * 32 + i * 16 + quad * 4 + reg;
                float d = znv[i][reg] + mc - 2.f * acc[i][j][reg];
                float r = (d + 1.0f) * __builtin_amdgcn_rcpf(d + EPSV);
                float r2 = r * r;
                float s = r2 * r2 * r;   // ratio^5 == exp(log(ratio)/0.2)
                if (ccls == rcls[i][reg]) {
                    pm[i][reg] = fmaxf(pm[i][reg], s);
                    cd[(size_t)(row0 + row) * 8 + (c & 7)] = d;
                } else {
                    ns[i][reg] += s;
                }
            }
        }
    }
    // reduce across the 16 lanes (l15) of each quad group
#pragma unroll
    for (int o = 1; o < 16; o <<= 1) {
#pragma unroll
        for (int i = 0; i < 2; ++i)
#pragma unroll
            for (int reg = 0; reg < 4; ++reg) {
                pm[i][reg] = fmaxf(pm[i][reg], __shfl_xor(pm[i][reg], o, 64));
                ns[i][reg] += __shfl_xor(ns[i][reg], o, 64);
            }
    }
    if (l15 == 0) {
#pragma unroll
        for (int i = 0; i < 2; ++i)
#pragma unroll
            for (int reg = 0; reg < 4; ++reg) {
                const int row = wr * 32 + i * 16 + quad * 4 + reg;
                spm[wc][row] = pm[i][reg];
                sns[wc][row] = ns[i][reg];
            }
    }
    __syncthreads();
    if (tid < BM) {
        float p = fmaxf(spm[0][tid], spm[1][tid]);
        float nsum = sns[0][tid] + sns[1][tid];
        float li = logf((nsum + p) / p);   // = -log(pos/(neg+pos))
#pragma unroll
        for (int o = 1; o < 64; o <<= 1) li += __shfl_xor(li, o, 64);
        if (tid == 0) atomicAdd(lossAcc, li);
    }
}

// ---------------------------------------------------------------------------
// Kernel 3: stage-1 top-32. One block per (motif, 4096-row chunk).
// Gathers same-class candidates to LDS (expected ~256, cap 512), then 32
// block-argmax rounds with exact (value desc, index asc) ordering.
// ---------------------------------------------------------------------------
__global__ __launch_bounds__(256) void sel1_k(const int* __restrict__ y,
                                              const float* __restrict__ cd,
                                              float* __restrict__ s1v,
                                              int* __restrict__ s1i) {
    __shared__ float ldv[512];
    __shared__ int   lidx[512];
    __shared__ int   cnt;
    __shared__ float rv[4];
    __shared__ int   ri[4], rp[4];

    const int bid = blockIdx.x;
    const int j = bid >> 3, chunk = bid & 7;
    const int cls = j >> 3, m8 = j & 7;
    const int tid = threadIdx.x;
    if (tid == 0) cnt = 0;
    __syncthreads();

    const int base = chunk * 4096;
    for (int t = tid; t < 4096; t += 256) {
        const int i = base + t;
        if (y[i] == cls) {
            int p = atomicAdd(&cnt, 1);
            if (p < 512) { ldv[p] = cd[(size_t)i * 8 + m8]; lidx[p] = i; }
        }
    }
    __syncthreads();
    const int n = cnt < 512 ? cnt : 512;

    for (int r = 0; r < KSEL; ++r) {
        float bv = -INFINITY;
        int bi = 0x7fffffff, bp = -1;
        for (int p = tid; p < n; p += 256) {
            float v = ldv[p];
            int ix = lidx[p];
            if (v > bv || (v == bv && ix < bi)) { bv = v; bi = ix; bp = p; }
        }
#pragma unroll
        for (int o = 1; o < 64; o <<= 1) {
            float ov = __shfl_xor(bv, o, 64);
            int   oi = __shfl_xor(bi, o, 64);
            int   op = __shfl_xor(bp, o, 64);
            if (ov > bv || (ov == bv && oi < bi)) { bv = ov; bi = oi; bp = op; }
        }
        if ((tid & 63) == 0) { int w = tid >> 6; rv[w] = bv; ri[w] = bi; rp[w] = bp; }
        __syncthreads();
        if (tid == 0) {
            float xv = rv[0]; int xi = ri[0], xp = rp[0];
            for (int w = 1; w < 4; ++w)
                if (rv[w] > xv || (rv[w] == xv && ri[w] < xi)) {
                    xv = rv[w]; xi = ri[w]; xp = rp[w];
                }
            s1v[(size_t)bid * KSEL + r] = xv;
            s1i[(size_t)bid * KSEL + r] = xi;
            ldv[xp] = -INFINITY;
        }
        __syncthreads();
    }
}

// ---------------------------------------------------------------------------
// Kernel 4: merge 8x32 stage-1 candidates -> global top-32, gather-mean of
// selected z rows, tau-blend, write. Block 0 writes the final loss.
// ---------------------------------------------------------------------------
__global__ __launch_bounds__(256) void merge_k(
    const float* __restrict__ z, const float* __restrict__ mv,
    const float* __restrict__ s1v, const int* __restrict__ s1i,
    const float* __restrict__ lossAcc, float* __restrict__ out) {
    __shared__ float ldv[256];
    __shared__ int   lidx[256];
    __shared__ int   sel[KSEL];
    __shared__ float rv[4];
    __shared__ int   ri[4], rp[4];

    const int j = blockIdx.x;
    const int tid = threadIdx.x;
    ldv[tid] = s1v[(size_t)j * 256 + tid];
    lidx[tid] = s1i[(size_t)j * 256 + tid];
    __syncthreads();

    for (int r = 0; r < KSEL; ++r) {
        float bv = ldv[tid];
        int bi = lidx[tid], bp = tid;
#pragma unroll
        for (int o = 1; o < 64; o <<= 1) {
            float ov = __shfl_xor(bv, o, 64);
            int   oi = __shfl_xor(bi, o, 64);
            int   op = __shfl_xor(bp, o, 64);
            if (ov > bv || (ov == bv && oi < bi)) { bv = ov; bi = oi; bp = op; }
        }
        if ((tid & 63) == 0) { int w = tid >> 6; rv[w] = bv; ri[w] = bi; rp[w] = bp; }
        __syncthreads();
        if (tid == 0) {
            float xv = rv[0]; int xi = ri[0], xp = rp[0];
            for (int w = 1; w < 4; ++w)
                if (rv[w] > xv || (rv[w] == xv && ri[w] < xi)) {
                    xv = rv[w]; xi = ri[w]; xp = rp[w];
                }
            sel[r] = xi;
            ldv[xp] = -INFINITY;
        }
        __syncthreads();
    }

    for (int h = tid; h < HD; h += 256) {
        float s = 0.f;
#pragma unroll 8
        for (int k = 0; k < KSEL; ++k) s += z[(size_t)sel[k] * HD + h];
        out[1 + (size_t)j * HD + h] =
            0.99f * mv[(size_t)j * HD + h] + 0.01f * (s * (1.0f / KSEL));
    }
    if (j == 0 && tid == 0) out[0] = lossAcc[0] * (1.0f / NROWS);
}

// ---------------------------------------------------------------------------
extern "C" void kernel_launch(void* const* d_in, const int* in_sizes, int n_in,
                              void* d_out, int out_size, void* d_ws, size_t ws_size,
                              hipStream_t stream) {
    const float* z  = (const float*)d_in[0];
    const float* mv = (const float*)d_in[1];
    const int*   y  = (const int*)d_in[2];
    float* out = (float*)d_out;
    float* wsf = (float*)d_ws;
    float*  mn   = wsf + WS_MN;
    __bf16* mvbf = (__bf16*)(wsf + WS_MVBF);
    float*  cd   = wsf + WS_CD;
    float*  s1v  = wsf + WS_S1V;
    int*    s1i  = (int*)(wsf + WS_S1I);

    hipLaunchKernelGGL(prep_k,     dim3(NMOT),       dim3(256), 0, stream, mv, wsf, mvbf);
    hipLaunchKernelGGL(gemm_fused, dim3(NROWS / BM), dim3(256), 0, stream, z, mvbf, mn, cd, y, wsf);
    hipLaunchKernelGGL(sel1_k,     dim3(NMOT * 8),   dim3(256), 0, stream, y, cd, s1v, s1i);
    hipLaunchKernelGGL(merge_k,    dim3(NMOT),       dim3(256), 0, stream, z, mv, s1v, s1i, wsf, out);
}